// Round 3
// baseline (219.464 us; speedup 1.0000x reference)
//
#include <hip/hip_runtime.h>

#define N_NODES 10000
#define N_EDGES 160000
#define NC 8
#define NB 64
#define LN_EPS 1e-5f

// ---------------- K1: histogram of dst and src ----------------
__global__ void hist_kernel(const int* __restrict__ edst, const int* __restrict__ esrc,
                            int* __restrict__ cnt_dst, int* __restrict__ cnt_src) {
  const int e = blockIdx.x * 256 + threadIdx.x;
  if (e < N_EDGES) {
    atomicAdd(&cnt_dst[edst[e]], 1);
    atomicAdd(&cnt_src[esrc[e]], 1);
  }
}

// ---------------- K2: exclusive scan (two blocks: dst, src) ----------------
__global__ void __launch_bounds__(1024) scan_kernel(
    const int* __restrict__ cnt_dst, const int* __restrict__ cnt_src,
    int* __restrict__ start_dst, int* __restrict__ cur_dst,
    int* __restrict__ start_src, int* __restrict__ cur_src) {
  const int* cnt = blockIdx.x ? cnt_src : cnt_dst;
  int* start = blockIdx.x ? start_src : start_dst;
  int* cur   = blockIdx.x ? cur_src   : cur_dst;

  const int t = threadIdx.x;
  const int lane = t & 63;
  const int wid = t >> 6;                 // 0..15
  const int lo = t * 10;
  const int hi = min(lo + 10, N_NODES);
  int s = 0;
  for (int i = lo; i < hi; ++i) s += cnt[i];
  const int own = s;
#pragma unroll
  for (int d = 1; d < 64; d <<= 1) {
    const int v = __shfl_up(s, d, 64);
    if (lane >= d) s += v;
  }
  __shared__ int wsum[16];
  if (lane == 63) wsum[wid] = s;
  __syncthreads();
  if (t == 0) {
    int acc = 0;
#pragma unroll
    for (int i = 0; i < 16; ++i) { acc += wsum[i]; wsum[i] = acc; }
  }
  __syncthreads();
  int base = (wid ? wsum[wid - 1] : 0) + s - own;
  for (int i = lo; i < hi; ++i) {
    start[i] = base;
    cur[i] = base;
    base += cnt[i];
  }
  if (t == 1023) start[N_NODES] = base;   // == N_EDGES
}

// ---------------- K3: prep — transpose x into DST-SORTED order + scatter weights ----
// For edge e with dst-rank p and src-rank q:
//   xT_d[p][b] = x[b][e]   (so node phase-1 reads are fully sequential)
//   w1_s[p]    = w1[e]
//   w3_s[q]    = w3[e]
//   sorted_src[q] = e      (only used as WRITE addresses in node phase-2)
__global__ void __launch_bounds__(256) prep_kernel(
    const float* __restrict__ x, const int* __restrict__ edst, const int* __restrict__ esrc,
    const float* __restrict__ w1, const float* __restrict__ w3,
    int* __restrict__ cur_dst, int* __restrict__ cur_src,
    float* __restrict__ xT_d, float* __restrict__ w1_s, float* __restrict__ w3_s,
    int* __restrict__ sorted_src) {
  __shared__ float tile[64][68];          // tile[e_local][b]
  __shared__ int pP[64];
  const int e0 = blockIdx.x * 64;
  const int t = threadIdx.x;

  if (t < 64) {
    const int e = e0 + t;
    const int p = atomicAdd(&cur_dst[edst[e]], 1);
    pP[t] = p;
    const int q = atomicAdd(&cur_src[esrc[e]], 1);
    sorted_src[q] = e;
    // scatter w1 -> w1_s[p], w3 -> w3_s[q] (32B rows; stores don't stall)
    const float4* wp1 = (const float4*)(w1 + (size_t)e * NC);
    float4* dp1 = (float4*)(w1_s + (size_t)p * NC);
    dp1[0] = wp1[0]; dp1[1] = wp1[1];
    const float4* wp3 = (const float4*)(w3 + (size_t)e * NC);
    float4* dp3 = (float4*)(w3_s + (size_t)q * NC);
    dp3[0] = wp3[0]; dp3[1] = wp3[1];
  }

  const int u = t & 15;                   // float4 group over inner dim
  const int row = t >> 4;                 // 0..15
#pragma unroll
  for (int j = 0; j < 4; ++j) {           // read x rows (b), float4 over e
    const int b = j * 16 + row;
    const float4 v = *(const float4*)&x[(size_t)b * N_EDGES + e0 + 4 * u];
    tile[4 * u + 0][b] = v.x; tile[4 * u + 1][b] = v.y;
    tile[4 * u + 2][b] = v.z; tile[4 * u + 3][b] = v.w;
  }
  __syncthreads();
#pragma unroll
  for (int j = 0; j < 4; ++j) {           // write row for local edge r to slot pP[r]
    const int r = j * 16 + row;
    const float4 v = *(const float4*)&tile[r][4 * u];
    *(float4*)&xT_d[(size_t)pP[r] * 64 + 4 * u] = v;
  }
}

// ---------------- K4: fused segment-sum + LN + ELU + src-side dot ----------------
// 256 threads = 4 nodes per block, lane b = batch index. Phase-1 reads are
// fully sequential (data pre-sorted) — no indirection in the load chain.
__global__ void __launch_bounds__(256) node_kernel(
    const float* __restrict__ xT_d, const float* __restrict__ w1_s,
    const float* __restrict__ b1, const float* __restrict__ gamma,
    const float* __restrict__ beta, const float* __restrict__ w3_s,
    const int* __restrict__ start_dst,
    const int* __restrict__ sorted_src, const int* __restrict__ start_src,
    float* __restrict__ outT) {
  const int n = blockIdx.x * 4 + (threadIdx.x >> 6);
  const int b = threadIdx.x & 63;

  float a[NC];
#pragma unroll
  for (int c = 0; c < NC; ++c) a[c] = 0.f;

  const int s0 = start_dst[n];
  const int s1 = start_dst[n + 1];
  int i = s0;
  for (; i + 4 <= s1; i += 4) {
    float xe[4];
#pragma unroll
    for (int k = 0; k < 4; ++k) xe[k] = xT_d[(size_t)(i + k) * 64 + b];
    float4 wla[4], wlb[4];
#pragma unroll
    for (int k = 0; k < 4; ++k) {
      const float4* wp = (const float4*)(w1_s + (size_t)(i + k) * NC);
      wla[k] = wp[0]; wlb[k] = wp[1];
    }
#pragma unroll
    for (int k = 0; k < 4; ++k) {
      a[0] += xe[k] * wla[k].x; a[1] += xe[k] * wla[k].y;
      a[2] += xe[k] * wla[k].z; a[3] += xe[k] * wla[k].w;
      a[4] += xe[k] * wlb[k].x; a[5] += xe[k] * wlb[k].y;
      a[6] += xe[k] * wlb[k].z; a[7] += xe[k] * wlb[k].w;
    }
  }
  for (; i < s1; ++i) {
    const float xe = xT_d[(size_t)i * 64 + b];
    const float4* wp = (const float4*)(w1_s + (size_t)i * NC);
    const float4 wa = wp[0], wb = wp[1];
    a[0] += xe * wa.x; a[1] += xe * wa.y; a[2] += xe * wa.z; a[3] += xe * wa.w;
    a[4] += xe * wb.x; a[5] += xe * wb.y; a[6] += xe * wb.z; a[7] += xe * wb.w;
  }

  // + b1, LayerNorm over C (in registers), gamma/beta, ELU
  const float4* b1p = (const float4*)(b1 + (size_t)n * NC);
  const float4 b1a = b1p[0], b1b = b1p[1];
  a[0] += b1a.x; a[1] += b1a.y; a[2] += b1a.z; a[3] += b1a.w;
  a[4] += b1b.x; a[5] += b1b.y; a[6] += b1b.z; a[7] += b1b.w;

  float mu = 0.f;
#pragma unroll
  for (int c = 0; c < NC; ++c) mu += a[c];
  mu *= 0.125f;
  float var = 0.f;
#pragma unroll
  for (int c = 0; c < NC; ++c) { a[c] -= mu; var += a[c] * a[c]; }
  var *= 0.125f;
  const float rs = rsqrtf(var + LN_EPS);

  const float4* gp = (const float4*)(gamma + (size_t)n * NC);
  const float4 ga = gp[0], gb = gp[1];
  const float4* bp = (const float4*)(beta + (size_t)n * NC);
  const float4 ba = bp[0], bb = bp[1];
  float v[NC];
  v[0] = a[0] * rs * ga.x + ba.x;  v[1] = a[1] * rs * ga.y + ba.y;
  v[2] = a[2] * rs * ga.z + ba.z;  v[3] = a[3] * rs * ga.w + ba.w;
  v[4] = a[4] * rs * gb.x + bb.x;  v[5] = a[5] * rs * gb.y + bb.y;
  v[6] = a[6] * rs * gb.z + bb.z;  v[7] = a[7] * rs * gb.w + bb.w;
#pragma unroll
  for (int c = 0; c < NC; ++c) v[c] = v[c] > 0.f ? v[c] : expm1f(v[c]);

  // src-side: w3_s reads sequential; outT writes scattered (stores don't stall)
  const int t0 = start_src[n];
  const int t1 = start_src[n + 1];
  int j = t0;
  for (; j + 4 <= t1; j += 4) {
    int ee[4];
#pragma unroll
    for (int k = 0; k < 4; ++k) ee[k] = sorted_src[j + k];
    float4 wla[4], wlb[4];
#pragma unroll
    for (int k = 0; k < 4; ++k) {
      const float4* wp = (const float4*)(w3_s + (size_t)(j + k) * NC);
      wla[k] = wp[0]; wlb[k] = wp[1];
    }
#pragma unroll
    for (int k = 0; k < 4; ++k) {
      const float dot = v[0] * wla[k].x + v[1] * wla[k].y + v[2] * wla[k].z + v[3] * wla[k].w +
                        v[4] * wlb[k].x + v[5] * wlb[k].y + v[6] * wlb[k].z + v[7] * wlb[k].w;
      outT[(size_t)ee[k] * 64 + b] = dot;
    }
  }
  for (; j < t1; ++j) {
    const int e = sorted_src[j];
    const float4* wp = (const float4*)(w3_s + (size_t)j * NC);
    const float4 wa = wp[0], wb = wp[1];
    const float dot = v[0] * wa.x + v[1] * wa.y + v[2] * wa.z + v[3] * wa.w +
                      v[4] * wb.x + v[5] * wb.y + v[6] * wb.z + v[7] * wb.w;
    outT[(size_t)e * 64 + b] = dot;
  }
}

// ---------------- K5: transpose outT (E,B) -> out (B,E), + b3 + x ----------------
__global__ void __launch_bounds__(256) finalize_kernel(
    const float* __restrict__ outT, const float* __restrict__ b3,
    const float* __restrict__ x, float* __restrict__ out) {
  __shared__ float tile[64][68];          // tile[b][e]
  const int e0 = blockIdx.x * 64;
  const int t = threadIdx.x;
  const int u = t & 15;
  const int row = t >> 4;
#pragma unroll
  for (int j = 0; j < 4; ++j) {           // read outT rows (e), float4 over b
    const int e = j * 16 + row;
    const float4 v = *(const float4*)&outT[(size_t)(e0 + e) * 64 + 4 * u];
    tile[4 * u + 0][e] = v.x; tile[4 * u + 1][e] = v.y;
    tile[4 * u + 2][e] = v.z; tile[4 * u + 3][e] = v.w;
  }
  __syncthreads();
  const float4 bb = *(const float4*)&b3[e0 + 4 * u];
#pragma unroll
  for (int j = 0; j < 4; ++j) {           // write out rows (b), float4 over e
    const int b = j * 16 + row;
    const float4 v = *(const float4*)&tile[b][4 * u];
    const float4 xb = *(const float4*)&x[(size_t)b * N_EDGES + e0 + 4 * u];
    float4 o;
    o.x = v.x + bb.x + xb.x;  o.y = v.y + bb.y + xb.y;
    o.z = v.z + bb.z + xb.z;  o.w = v.w + bb.w + xb.w;
    *(float4*)&out[(size_t)b * N_EDGES + e0 + 4 * u] = o;
  }
}

extern "C" void kernel_launch(void* const* d_in, const int* in_sizes, int n_in,
                              void* d_out, int out_size, void* d_ws, size_t ws_size,
                              hipStream_t stream) {
  const float* x     = (const float*)d_in[0];
  const float* w1    = (const float*)d_in[1];
  const float* b1    = (const float*)d_in[2];
  const float* gamma = (const float*)d_in[3];
  const float* beta  = (const float*)d_in[4];
  const float* w3    = (const float*)d_in[5];
  const float* b3    = (const float*)d_in[6];
  const int* esrc    = (const int*)d_in[7];
  const int* edst    = (const int*)d_in[8];
  float* out = (float*)d_out;

  char* ws = (char*)d_ws;
  size_t off = 0;
  auto alloc = [&](size_t bytes) -> void* {
    void* p = ws + off;
    off += (bytes + 255) & ~(size_t)255;
    return p;
  };
  float* xT_d      = (float*)alloc((size_t)N_EDGES * NB * 4);
  float* outT      = (float*)alloc((size_t)N_EDGES * NB * 4);
  float* w1_s      = (float*)alloc((size_t)N_EDGES * NC * 4);
  float* w3_s      = (float*)alloc((size_t)N_EDGES * NC * 4);
  int* cnt_dst     = (int*)alloc((size_t)N_NODES * 4);
  int* cnt_src     = (int*)alloc((size_t)N_NODES * 4);
  int* start_dst   = (int*)alloc((size_t)(N_NODES + 1) * 4);
  int* start_src   = (int*)alloc((size_t)(N_NODES + 1) * 4);
  int* cur_dst     = (int*)alloc((size_t)N_NODES * 4);
  int* cur_src     = (int*)alloc((size_t)N_NODES * 4);
  int* sorted_src  = (int*)alloc((size_t)N_EDGES * 4);

  // zero both histograms (ws is re-poisoned to 0xAA before every launch)
  hipMemsetAsync(cnt_dst, 0, (size_t)2 * N_NODES * 4 + 512, stream);

  hist_kernel<<<N_EDGES / 256, 256, 0, stream>>>(edst, esrc, cnt_dst, cnt_src);
  scan_kernel<<<2, 1024, 0, stream>>>(cnt_dst, cnt_src, start_dst, cur_dst, start_src, cur_src);
  prep_kernel<<<N_EDGES / 64, 256, 0, stream>>>(x, edst, esrc, w1, w3,
                                                cur_dst, cur_src,
                                                xT_d, w1_s, w3_s, sorted_src);
  node_kernel<<<N_NODES / 4, 256, 0, stream>>>(xT_d, w1_s, b1, gamma, beta, w3_s,
                                               start_dst, sorted_src, start_src, outT);
  finalize_kernel<<<N_EDGES / 64, 256, 0, stream>>>(outT, b3, x, out);
}

// Round 4
// 216.499 us; speedup vs baseline: 1.0137x; 1.0137x over previous
//
#include <hip/hip_runtime.h>

#define N_NODES 10000
#define N_EDGES 160000
#define NC 8
#define LN_EPS 1e-5f

// Conflict-free LDS transpose swizzle: element (e_local, b) of a 64x64 tile.
// Keeps b-groups-of-4 contiguous (float4-readable over b), XOR on the group
// index makes both scalar column writes and float4 row reads <=2-way.
__device__ __forceinline__ int swz(int e, int b) {
  return e * 64 + ((((b >> 2) ^ ((e >> 2) & 15)) << 2) | (b & 3));
}

// ---------------- K1: histogram of dst ----------------
__global__ void hist_kernel(const int* __restrict__ edst, int* __restrict__ cnt_dst) {
  const int e = blockIdx.x * 256 + threadIdx.x;
  if (e < N_EDGES) atomicAdd(&cnt_dst[edst[e]], 1);
}

// ---------------- K2: exclusive scan over dst counts (1 block) ----------------
__global__ void __launch_bounds__(1024) scan_kernel(
    const int* __restrict__ cnt, int* __restrict__ start, int* __restrict__ cur) {
  const int t = threadIdx.x;
  const int lane = t & 63;
  const int wid = t >> 6;                 // 0..15
  const int lo = t * 10;
  const int hi = min(lo + 10, N_NODES);
  int s = 0;
  for (int i = lo; i < hi; ++i) s += cnt[i];
  const int own = s;
#pragma unroll
  for (int d = 1; d < 64; d <<= 1) {
    const int v = __shfl_up(s, d, 64);
    if (lane >= d) s += v;
  }
  __shared__ int wsum[16];
  if (lane == 63) wsum[wid] = s;
  __syncthreads();
  if (t == 0) {
    int acc = 0;
#pragma unroll
    for (int i = 0; i < 16; ++i) { acc += wsum[i]; wsum[i] = acc; }
  }
  __syncthreads();
  int base = (wid ? wsum[wid - 1] : 0) + s - own;
  for (int i = lo; i < hi; ++i) {
    start[i] = base;
    cur[i] = base;
    base += cnt[i];
  }
  if (t == 1023) start[N_NODES] = base;   // == N_EDGES
}

// ---------------- K3: prep — transpose x into DST-SORTED order + scatter w1 ----
// Edge e with dst-rank p:  xT_d[p][b] = x[b][e],  w1_s[p] = w1[e].
__global__ void __launch_bounds__(256) prep_kernel(
    const float* __restrict__ x, const int* __restrict__ edst,
    const float* __restrict__ w1, int* __restrict__ cur_dst,
    float* __restrict__ xT_d, float* __restrict__ w1_s) {
  __shared__ float tile[64 * 64];
  __shared__ int pP[64];
  const int e0 = blockIdx.x * 64;
  const int t = threadIdx.x;

  if (t < 64) {
    const int e = e0 + t;
    const int p = atomicAdd(&cur_dst[edst[e]], 1);
    pP[t] = p;
    const float4* wp1 = (const float4*)(w1 + (size_t)e * NC);
    float4* dp1 = (float4*)(w1_s + (size_t)p * NC);
    dp1[0] = wp1[0]; dp1[1] = wp1[1];
  }

  const int u = t & 15;                   // float4 group over e on load
  const int row = t >> 4;                 // 0..15
#pragma unroll
  for (int j = 0; j < 4; ++j) {           // read x rows (b), float4 over e
    const int b = j * 16 + row;
    const float4 xv = *(const float4*)&x[(size_t)b * N_EDGES + e0 + 4 * u];
    tile[swz(4 * u + 0, b)] = xv.x;
    tile[swz(4 * u + 1, b)] = xv.y;
    tile[swz(4 * u + 2, b)] = xv.z;
    tile[swz(4 * u + 3, b)] = xv.w;
  }
  __syncthreads();
#pragma unroll
  for (int j = 0; j < 4; ++j) {           // write sorted row: float4 over b
    const int r = j * 16 + row;
    const float4 vv = *(const float4*)&tile[r * 64 + ((u ^ ((r >> 2) & 15)) << 2)];
    *(float4*)&xT_d[(size_t)pP[r] * 64 + 4 * u] = vv;
  }
}

// ---------------- K4: segment-sum + LN + ELU -> node features v[n][b][c] ------
// 256 threads = 4 nodes/block, lane = b. Reads fully sequential (pre-sorted).
__global__ void __launch_bounds__(256) node_kernel(
    const float* __restrict__ xT_d, const float* __restrict__ w1_s,
    const float* __restrict__ b1, const float* __restrict__ gamma,
    const float* __restrict__ beta, const int* __restrict__ start_dst,
    float* __restrict__ v) {
  const int n = blockIdx.x * 4 + (threadIdx.x >> 6);
  const int b = threadIdx.x & 63;

  float a[NC];
#pragma unroll
  for (int c = 0; c < NC; ++c) a[c] = 0.f;

  const int s0 = start_dst[n];
  const int s1 = start_dst[n + 1];
  int i = s0;
  for (; i + 4 <= s1; i += 4) {
    float xe[4];
#pragma unroll
    for (int k = 0; k < 4; ++k) xe[k] = xT_d[(size_t)(i + k) * 64 + b];
    float4 wla[4], wlb[4];
#pragma unroll
    for (int k = 0; k < 4; ++k) {
      const float4* wp = (const float4*)(w1_s + (size_t)(i + k) * NC);
      wla[k] = wp[0]; wlb[k] = wp[1];
    }
#pragma unroll
    for (int k = 0; k < 4; ++k) {
      a[0] += xe[k] * wla[k].x; a[1] += xe[k] * wla[k].y;
      a[2] += xe[k] * wla[k].z; a[3] += xe[k] * wla[k].w;
      a[4] += xe[k] * wlb[k].x; a[5] += xe[k] * wlb[k].y;
      a[6] += xe[k] * wlb[k].z; a[7] += xe[k] * wlb[k].w;
    }
  }
  for (; i < s1; ++i) {
    const float xe = xT_d[(size_t)i * 64 + b];
    const float4* wp = (const float4*)(w1_s + (size_t)i * NC);
    const float4 wa = wp[0], wb = wp[1];
    a[0] += xe * wa.x; a[1] += xe * wa.y; a[2] += xe * wa.z; a[3] += xe * wa.w;
    a[4] += xe * wb.x; a[5] += xe * wb.y; a[6] += xe * wb.z; a[7] += xe * wb.w;
  }

  const float4* b1p = (const float4*)(b1 + (size_t)n * NC);
  const float4 b1a = b1p[0], b1b = b1p[1];
  a[0] += b1a.x; a[1] += b1a.y; a[2] += b1a.z; a[3] += b1a.w;
  a[4] += b1b.x; a[5] += b1b.y; a[6] += b1b.z; a[7] += b1b.w;

  float mu = 0.f;
#pragma unroll
  for (int c = 0; c < NC; ++c) mu += a[c];
  mu *= 0.125f;
  float var = 0.f;
#pragma unroll
  for (int c = 0; c < NC; ++c) { a[c] -= mu; var += a[c] * a[c]; }
  var *= 0.125f;
  const float rs = rsqrtf(var + LN_EPS);

  const float4* gp = (const float4*)(gamma + (size_t)n * NC);
  const float4 ga = gp[0], gb = gp[1];
  const float4* bp = (const float4*)(beta + (size_t)n * NC);
  const float4 ba = bp[0], bb = bp[1];
  float w[NC];
  w[0] = a[0] * rs * ga.x + ba.x;  w[1] = a[1] * rs * ga.y + ba.y;
  w[2] = a[2] * rs * ga.z + ba.z;  w[3] = a[3] * rs * ga.w + ba.w;
  w[4] = a[4] * rs * gb.x + bb.x;  w[5] = a[5] * rs * gb.y + bb.y;
  w[6] = a[6] * rs * gb.z + bb.z;  w[7] = a[7] * rs * gb.w + bb.w;
#pragma unroll
  for (int c = 0; c < NC; ++c) w[c] = w[c] > 0.f ? w[c] : expm1f(w[c]);

  // v[n][b][0..7] — 2 float4 stores, 2KB contiguous per wave
  float4* vp = (float4*)(v + (size_t)n * 512 + b * NC);
  float4 o0, o1;
  o0.x = w[0]; o0.y = w[1]; o0.z = w[2]; o0.w = w[3];
  o1.x = w[4]; o1.y = w[5]; o1.z = w[6]; o1.w = w[7];
  vp[0] = o0; vp[1] = o1;
}

// ---------------- K5: edge kernel — gather v[src], dot w3, +b3+x -> out --------
// 64 edges/block; 4 waves x 16 edges. v rows are 2KB contiguous (coalesced
// gather, L2/L3-resident). LDS transpose -> coalesced float4 out writes.
__global__ void __launch_bounds__(256) edge_kernel(
    const float* __restrict__ v, const float* __restrict__ w3,
    const float* __restrict__ b3, const float* __restrict__ x,
    const int* __restrict__ esrc, float* __restrict__ out) {
  __shared__ float tile[64 * 64];
  const int e0 = blockIdx.x * 64;
  const int t = threadIdx.x;
  const int w = t >> 6;                   // wave 0..3 -> edges w*16..w*16+15
  const int b = t & 63;

  int sidx = 0;
  if (b < 16) sidx = esrc[e0 + w * 16 + b];

#pragma unroll 4
  for (int r = 0; r < 16; ++r) {
    const int s = __shfl(sidx, r, 64);
    const float4* vp = (const float4*)(v + (size_t)s * 512 + b * NC);
    const float4 va = vp[0], vb = vp[1];
    const float4* wp = (const float4*)(w3 + (size_t)(e0 + w * 16 + r) * NC);
    const float4 wa = wp[0], wb = wp[1];
    const float dot = va.x * wa.x + va.y * wa.y + va.z * wa.z + va.w * wa.w +
                      vb.x * wb.x + vb.y * wb.y + vb.z * wb.z + vb.w * wb.w;
    tile[swz(w * 16 + r, b)] = dot;
  }
  __syncthreads();

  const int u = t & 15;
  const int row = t >> 4;                 // 0..15
  const float4 bb = *(const float4*)&b3[e0 + 4 * u];
#pragma unroll
  for (int j = 0; j < 4; ++j) {
    const int bo = j * 16 + row;
    const float o0 = tile[swz(4 * u + 0, bo)];
    const float o1 = tile[swz(4 * u + 1, bo)];
    const float o2 = tile[swz(4 * u + 2, bo)];
    const float o3 = tile[swz(4 * u + 3, bo)];
    const float4 xb = *(const float4*)&x[(size_t)bo * N_EDGES + e0 + 4 * u];
    float4 o;
    o.x = o0 + bb.x + xb.x;  o.y = o1 + bb.y + xb.y;
    o.z = o2 + bb.z + xb.z;  o.w = o3 + bb.w + xb.w;
    *(float4*)&out[(size_t)bo * N_EDGES + e0 + 4 * u] = o;
  }
}

extern "C" void kernel_launch(void* const* d_in, const int* in_sizes, int n_in,
                              void* d_out, int out_size, void* d_ws, size_t ws_size,
                              hipStream_t stream) {
  const float* x     = (const float*)d_in[0];
  const float* w1    = (const float*)d_in[1];
  const float* b1    = (const float*)d_in[2];
  const float* gamma = (const float*)d_in[3];
  const float* beta  = (const float*)d_in[4];
  const float* w3    = (const float*)d_in[5];
  const float* b3    = (const float*)d_in[6];
  const int* esrc    = (const int*)d_in[7];
  const int* edst    = (const int*)d_in[8];
  float* out = (float*)d_out;

  char* ws = (char*)d_ws;
  size_t off = 0;
  auto alloc = [&](size_t bytes) -> void* {
    void* p = ws + off;
    off += (bytes + 255) & ~(size_t)255;
    return p;
  };
  float* xT_d      = (float*)alloc((size_t)N_EDGES * 64 * 4);
  float* w1_s      = (float*)alloc((size_t)N_EDGES * NC * 4);
  float* v         = (float*)alloc((size_t)N_NODES * 512 * 4);
  int* cnt_dst     = (int*)alloc((size_t)N_NODES * 4);
  int* start_dst   = (int*)alloc((size_t)(N_NODES + 1) * 4);
  int* cur_dst     = (int*)alloc((size_t)N_NODES * 4);

  hipMemsetAsync(cnt_dst, 0, (size_t)N_NODES * 4, stream);

  hist_kernel<<<N_EDGES / 256, 256, 0, stream>>>(edst, cnt_dst);
  scan_kernel<<<1, 1024, 0, stream>>>(cnt_dst, start_dst, cur_dst);
  prep_kernel<<<N_EDGES / 64, 256, 0, stream>>>(x, edst, w1, cur_dst, xT_d, w1_s);
  node_kernel<<<N_NODES / 4, 256, 0, stream>>>(xT_d, w1_s, b1, gamma, beta,
                                               start_dst, v);
  edge_kernel<<<N_EDGES / 64, 256, 0, stream>>>(v, w3, b3, x, esrc, out);
}

// Round 5
// 193.742 us; speedup vs baseline: 1.1328x; 1.1175x over previous
//
#include <hip/hip_runtime.h>

#define N_NODES 10000
#define N_EDGES 160000
#define NC 8
#define LN_EPS 1e-5f

typedef _Float16 h4_t __attribute__((ext_vector_type(4)));
typedef _Float16 h8_t __attribute__((ext_vector_type(8)));

// Conflict-free LDS transpose swizzle for a 64x64 fp32 tile.
__device__ __forceinline__ int swz(int e, int b) {
  return e * 64 + ((((b >> 2) ^ ((e >> 2) & 15)) << 2) | (b & 3));
}

// ---------------- K1: histogram of dst ----------------
__global__ void hist_kernel(const int* __restrict__ edst, int* __restrict__ cnt_dst) {
  const int e = blockIdx.x * 256 + threadIdx.x;
  if (e < N_EDGES) atomicAdd(&cnt_dst[edst[e]], 1);
}

// ---------------- K2: exclusive scan over dst counts (1 block) ----------------
__global__ void __launch_bounds__(1024) scan_kernel(
    const int* __restrict__ cnt, int* __restrict__ start, int* __restrict__ cur) {
  const int t = threadIdx.x;
  const int lane = t & 63;
  const int wid = t >> 6;                 // 0..15
  const int lo = t * 10;
  const int hi = min(lo + 10, N_NODES);
  int s = 0;
  for (int i = lo; i < hi; ++i) s += cnt[i];
  const int own = s;
#pragma unroll
  for (int d = 1; d < 64; d <<= 1) {
    const int v = __shfl_up(s, d, 64);
    if (lane >= d) s += v;
  }
  __shared__ int wsum[16];
  if (lane == 63) wsum[wid] = s;
  __syncthreads();
  if (t == 0) {
    int acc = 0;
#pragma unroll
    for (int i = 0; i < 16; ++i) { acc += wsum[i]; wsum[i] = acc; }
  }
  __syncthreads();
  int base = (wid ? wsum[wid - 1] : 0) + s - own;
  for (int i = lo; i < hi; ++i) {
    start[i] = base;
    cur[i] = base;
    base += cnt[i];
  }
  if (t == 1023) start[N_NODES] = base;   // == N_EDGES
}

// ---------------- K3: prep — transpose x into DST-SORTED fp16 rows -----------
// Edge e with dst-rank p: xT_d[p][b] = (fp16)x[b][e]; sorted_dst[p] = e.
// fp16 row = 128 B = exactly one cache line -> scatter writes don't amplify.
__global__ void __launch_bounds__(256) prep_kernel(
    const float* __restrict__ x, const int* __restrict__ edst,
    int* __restrict__ cur_dst, _Float16* __restrict__ xT_d,
    int* __restrict__ sorted_dst) {
  __shared__ float tile[64 * 64];
  __shared__ int pP[64];
  const int e0 = blockIdx.x * 64;
  const int t = threadIdx.x;

  if (t < 64) {
    const int e = e0 + t;
    const int p = atomicAdd(&cur_dst[edst[e]], 1);
    pP[t] = p;
    sorted_dst[p] = e;
  }

  const int u = t & 15;
  const int row = t >> 4;                 // 0..15
#pragma unroll
  for (int j = 0; j < 4; ++j) {           // read x rows (b), float4 over e
    const int b = j * 16 + row;
    const float4 xv = *(const float4*)&x[(size_t)b * N_EDGES + e0 + 4 * u];
    tile[swz(4 * u + 0, b)] = xv.x;
    tile[swz(4 * u + 1, b)] = xv.y;
    tile[swz(4 * u + 2, b)] = xv.z;
    tile[swz(4 * u + 3, b)] = xv.w;
  }
  __syncthreads();
#pragma unroll
  for (int j = 0; j < 4; ++j) {           // write sorted fp16 row: half4 over b
    const int r = j * 16 + row;
    const float4 vv = *(const float4*)&tile[r * 64 + ((u ^ ((r >> 2) & 15)) << 2)];
    h4_t hv;
    hv[0] = (_Float16)vv.x; hv[1] = (_Float16)vv.y;
    hv[2] = (_Float16)vv.z; hv[3] = (_Float16)vv.w;
    *(h4_t*)&xT_d[(size_t)pP[r] * 64 + 4 * u] = hv;
  }
}

// ---------------- K4: segment-sum + LN + ELU -> v[n][b][c] (fp16) -------------
// 4 nodes/block, lane = b. xT_d reads sequential; w1 via sorted id (32B bcast).
__global__ void __launch_bounds__(256) node_kernel(
    const _Float16* __restrict__ xT_d, const int* __restrict__ sorted_dst,
    const float* __restrict__ w1, const float* __restrict__ b1,
    const float* __restrict__ gamma, const float* __restrict__ beta,
    const int* __restrict__ start_dst, _Float16* __restrict__ v) {
  const int n = blockIdx.x * 4 + (threadIdx.x >> 6);
  const int b = threadIdx.x & 63;

  float a[NC];
#pragma unroll
  for (int c = 0; c < NC; ++c) a[c] = 0.f;

  const int s0 = start_dst[n];
  const int s1 = start_dst[n + 1];
  int i = s0;
  for (; i + 4 <= s1; i += 4) {
    int ee[4];
#pragma unroll
    for (int k = 0; k < 4; ++k) ee[k] = sorted_dst[i + k];
    float xe[4];
#pragma unroll
    for (int k = 0; k < 4; ++k) xe[k] = (float)xT_d[(size_t)(i + k) * 64 + b];
    float4 wla[4], wlb[4];
#pragma unroll
    for (int k = 0; k < 4; ++k) {
      const float4* wp = (const float4*)(w1 + (size_t)ee[k] * NC);
      wla[k] = wp[0]; wlb[k] = wp[1];
    }
#pragma unroll
    for (int k = 0; k < 4; ++k) {
      a[0] += xe[k] * wla[k].x; a[1] += xe[k] * wla[k].y;
      a[2] += xe[k] * wla[k].z; a[3] += xe[k] * wla[k].w;
      a[4] += xe[k] * wlb[k].x; a[5] += xe[k] * wlb[k].y;
      a[6] += xe[k] * wlb[k].z; a[7] += xe[k] * wlb[k].w;
    }
  }
  for (; i < s1; ++i) {
    const int e = sorted_dst[i];
    const float xe = (float)xT_d[(size_t)i * 64 + b];
    const float4* wp = (const float4*)(w1 + (size_t)e * NC);
    const float4 wa = wp[0], wb = wp[1];
    a[0] += xe * wa.x; a[1] += xe * wa.y; a[2] += xe * wa.z; a[3] += xe * wa.w;
    a[4] += xe * wb.x; a[5] += xe * wb.y; a[6] += xe * wb.z; a[7] += xe * wb.w;
  }

  const float4* b1p = (const float4*)(b1 + (size_t)n * NC);
  const float4 b1a = b1p[0], b1b = b1p[1];
  a[0] += b1a.x; a[1] += b1a.y; a[2] += b1a.z; a[3] += b1a.w;
  a[4] += b1b.x; a[5] += b1b.y; a[6] += b1b.z; a[7] += b1b.w;

  float mu = 0.f;
#pragma unroll
  for (int c = 0; c < NC; ++c) mu += a[c];
  mu *= 0.125f;
  float var = 0.f;
#pragma unroll
  for (int c = 0; c < NC; ++c) { a[c] -= mu; var += a[c] * a[c]; }
  var *= 0.125f;
  const float rs = rsqrtf(var + LN_EPS);

  const float4* gp = (const float4*)(gamma + (size_t)n * NC);
  const float4 ga = gp[0], gb = gp[1];
  const float4* bp = (const float4*)(beta + (size_t)n * NC);
  const float4 ba = bp[0], bb = bp[1];
  float w[NC];
  w[0] = a[0] * rs * ga.x + ba.x;  w[1] = a[1] * rs * ga.y + ba.y;
  w[2] = a[2] * rs * ga.z + ba.z;  w[3] = a[3] * rs * ga.w + ba.w;
  w[4] = a[4] * rs * gb.x + bb.x;  w[5] = a[5] * rs * gb.y + bb.y;
  w[6] = a[6] * rs * gb.z + bb.z;  w[7] = a[7] * rs * gb.w + bb.w;
#pragma unroll
  for (int c = 0; c < NC; ++c) w[c] = w[c] > 0.f ? w[c] : expm1f(w[c]);

  h8_t hv;
#pragma unroll
  for (int c = 0; c < NC; ++c) hv[c] = (_Float16)w[c];
  *(h8_t*)&v[(size_t)n * 512 + b * NC] = hv;     // wave writes 1KB contiguous
}

// ---------------- K5: edge kernel — gather v[src] (fp16), dot w3, +b3+x ------
__global__ void __launch_bounds__(256) edge_kernel(
    const _Float16* __restrict__ v, const float* __restrict__ w3,
    const float* __restrict__ b3, const float* __restrict__ x,
    const int* __restrict__ esrc, float* __restrict__ out) {
  __shared__ float tile[64 * 64];
  const int e0 = blockIdx.x * 64;
  const int t = threadIdx.x;
  const int w = t >> 6;                   // wave 0..3 -> edges w*16..w*16+15
  const int b = t & 63;

  int sidx = 0;
  if (b < 16) sidx = esrc[e0 + w * 16 + b];

#pragma unroll 8
  for (int r = 0; r < 16; ++r) {
    const int s = __shfl(sidx, r, 64);
    const h8_t hv = *(const h8_t*)&v[(size_t)s * 512 + b * NC];  // 16B/lane, 1KB/wave
    const float4* wp = (const float4*)(w3 + (size_t)(e0 + w * 16 + r) * NC);
    const float4 wa = wp[0], wb = wp[1];
    const float dot =
        (float)hv[0] * wa.x + (float)hv[1] * wa.y + (float)hv[2] * wa.z + (float)hv[3] * wa.w +
        (float)hv[4] * wb.x + (float)hv[5] * wb.y + (float)hv[6] * wb.z + (float)hv[7] * wb.w;
    tile[swz(w * 16 + r, b)] = dot;
  }
  __syncthreads();

  const int u = t & 15;
  const int row = t >> 4;                 // 0..15
  const float4 bb = *(const float4*)&b3[e0 + 4 * u];
#pragma unroll
  for (int j = 0; j < 4; ++j) {
    const int bo = j * 16 + row;
    const float o0 = tile[swz(4 * u + 0, bo)];
    const float o1 = tile[swz(4 * u + 1, bo)];
    const float o2 = tile[swz(4 * u + 2, bo)];
    const float o3 = tile[swz(4 * u + 3, bo)];
    const float4 xb = *(const float4*)&x[(size_t)bo * N_EDGES + e0 + 4 * u];
    float4 o;
    o.x = o0 + bb.x + xb.x;  o.y = o1 + bb.y + xb.y;
    o.z = o2 + bb.z + xb.z;  o.w = o3 + bb.w + xb.w;
    *(float4*)&out[(size_t)bo * N_EDGES + e0 + 4 * u] = o;
  }
}

extern "C" void kernel_launch(void* const* d_in, const int* in_sizes, int n_in,
                              void* d_out, int out_size, void* d_ws, size_t ws_size,
                              hipStream_t stream) {
  const float* x     = (const float*)d_in[0];
  const float* w1    = (const float*)d_in[1];
  const float* b1    = (const float*)d_in[2];
  const float* gamma = (const float*)d_in[3];
  const float* beta  = (const float*)d_in[4];
  const float* w3    = (const float*)d_in[5];
  const float* b3    = (const float*)d_in[6];
  const int* esrc    = (const int*)d_in[7];
  const int* edst    = (const int*)d_in[8];
  float* out = (float*)d_out;

  char* ws = (char*)d_ws;
  size_t off = 0;
  auto alloc = [&](size_t bytes) -> void* {
    void* p = ws + off;
    off += (bytes + 255) & ~(size_t)255;
    return p;
  };
  _Float16* xT_d   = (_Float16*)alloc((size_t)N_EDGES * 64 * 2);
  _Float16* v      = (_Float16*)alloc((size_t)N_NODES * 512 * 2);
  int* sorted_dst  = (int*)alloc((size_t)N_EDGES * 4);
  int* cnt_dst     = (int*)alloc((size_t)N_NODES * 4);
  int* start_dst   = (int*)alloc((size_t)(N_NODES + 1) * 4);
  int* cur_dst     = (int*)alloc((size_t)N_NODES * 4);

  hipMemsetAsync(cnt_dst, 0, (size_t)N_NODES * 4, stream);

  hist_kernel<<<N_EDGES / 256, 256, 0, stream>>>(edst, cnt_dst);
  scan_kernel<<<1, 1024, 0, stream>>>(cnt_dst, start_dst, cur_dst);
  prep_kernel<<<N_EDGES / 64, 256, 0, stream>>>(x, edst, cur_dst, xT_d, sorted_dst);
  node_kernel<<<N_NODES / 4, 256, 0, stream>>>(xT_d, sorted_dst, w1, b1, gamma, beta,
                                               start_dst, v);
  edge_kernel<<<N_EDGES / 64, 256, 0, stream>>>(v, w3, b3, x, esrc, out);
}